// Round 1
// baseline (11363.153 us; speedup 1.0000x reference)
//
#include <hip/hip_runtime.h>
#include <hip/hip_bf16.h>

typedef __bf16 bf16x8 __attribute__((ext_vector_type(8)));
typedef __bf16 bf16x4 __attribute__((ext_vector_type(4)));
typedef float  f32x4  __attribute__((ext_vector_type(4)));
typedef float  f32x16 __attribute__((ext_vector_type(16)));

// Problem dims
#define NB 64
#define NT 512
#define ND 512
#define NH 1024
#define NG 4096  // 4H

// workspace layout (bytes)
#define OFF_BAR 0u          // barrier: flag@0, root@128, grp[i]@256+i*128
#define OFF_H   4096u       // h double buffer: 2 x 64 x 1024 bf16 = 256 KB
#define OFF_EB  266240u     // E as bf16: 32000x512
#define OFF_WT  33034240u   // W^T bf16: 4096x512
#define OFF_UT  37228544u   // U^T bf16: 4096x1024
#define OFF_XW  45617152u   // xw bf16: (T,B,4096) = 256 MB
// total = 314,052,608 bytes

__device__ __forceinline__ void gl_lds16(const void* g, void* l) {
  typedef const unsigned __attribute__((address_space(1)))* gp_t;
  typedef unsigned __attribute__((address_space(3)))* lp_t;
  __builtin_amdgcn_global_load_lds((gp_t)g, (lp_t)l, 16, 0, 0);
}

__device__ __forceinline__ float sigf(float x) {
  return 1.0f / (1.0f + __expf(-x));
}

// ---------------- prep kernels ----------------
__global__ void k_zero(uint4* p, int n) {
  int i = blockIdx.x * blockDim.x + threadIdx.x;
  int stride = gridDim.x * blockDim.x;
  uint4 z; z.x = 0; z.y = 0; z.z = 0; z.w = 0;
  for (; i < n; i += stride) p[i] = z;
}

__global__ void k_cvt(const float* __restrict__ in, __bf16* __restrict__ out, int n4) {
  int i = blockIdx.x * blockDim.x + threadIdx.x;
  int stride = gridDim.x * blockDim.x;
  for (; i < n4; i += stride) {
    float4 f = ((const float4*)in)[i];
    bf16x4 o;
    o.x = (__bf16)f.x; o.y = (__bf16)f.y; o.z = (__bf16)f.z; o.w = (__bf16)f.w;
    ((bf16x4*)out)[i] = o;
  }
}

// out[c][r] = (bf16) in[r][c];  in is (R,C) f32, out is (C,R) bf16
__global__ void k_transpose(const float* __restrict__ in, __bf16* __restrict__ out,
                            int R, int C) {
  __shared__ __bf16 tile[64][72];
  int c0 = blockIdx.x * 64, r0 = blockIdx.y * 64;
  for (int i = threadIdx.x; i < 4096; i += 256) {
    int r = i >> 6, c = i & 63;
    tile[r][c] = (__bf16)in[(size_t)(r0 + r) * C + c0 + c];
  }
  __syncthreads();
  for (int i = threadIdx.x; i < 4096; i += 256) {
    int c = i >> 6, r = i & 63;
    out[(size_t)(c0 + c) * R + r0 + r] = tile[r][c];
  }
}

// ---------------- GEMM1: xw[t][b][g] = E[ids[bt]] @ W + b ----------------
// M=32768 (bt), N=4096 (g), K=512. 128x128 tile, BK=64, 4 waves each 64x64.
__global__ __launch_bounds__(256, 2) void k_gemm_xw(
    const int* __restrict__ ids, const __bf16* __restrict__ Ebf,
    const __bf16* __restrict__ Wt, const float* __restrict__ bias,
    __bf16* __restrict__ xw) {
  __shared__ __align__(16) char smem[32768];  // A tile 16K + B tile 16K
  char* ldsA = smem;
  char* ldsB = smem + 16384;

  const int tid = threadIdx.x;
  const int lane = tid & 63, w = tid >> 6;
  const int bm = blockIdx.x >> 5;          // 0..255
  const int bn0 = (blockIdx.x & 31) * 128; // col base

  // staging addressing: lane covers (row = w*32 + is*8 + (lane>>3), phys chunk pc = lane&7)
  const int l8r = lane >> 3, pc = lane & 7;
  size_t asrc[4], bsrc[4];
#pragma unroll
  for (int is = 0; is < 4; ++is) {
    int row = w * 32 + is * 8 + l8r;
    int id = ids[bm * 128 + row];
    asrc[is] = (size_t)id * ND + (size_t)(((pc ^ (row & 7)) * 8));
    int gn = bn0 + row;
    bsrc[is] = (size_t)gn * ND + (size_t)(((pc ^ (row & 7)) * 8));
  }

  const int rm = (w & 1) * 64, cn = (w >> 1) * 64;
  const int l31 = lane & 31, l5 = lane >> 5;
  f32x16 acc[2][2] = {};

  for (int kk = 0; kk < 8; ++kk) {
#pragma unroll
    for (int is = 0; is < 4; ++is) {
      gl_lds16(Ebf + asrc[is] + kk * 64, ldsA + w * 4096 + is * 1024);
      gl_lds16(Wt + bsrc[is] + kk * 64, ldsB + w * 4096 + is * 1024);
    }
    __syncthreads();
#pragma unroll
    for (int ksub = 0; ksub < 4; ++ksub) {
      int c = ksub * 2 + l5;
      bf16x8 af[2], bfr[2];
#pragma unroll
      for (int mt = 0; mt < 2; ++mt) {
        int row = rm + mt * 32 + l31;
        af[mt] = *(const bf16x8*)(ldsA + row * 128 + ((c ^ (row & 7)) << 4));
      }
#pragma unroll
      for (int nt = 0; nt < 2; ++nt) {
        int rowb = cn + nt * 32 + l31;
        bfr[nt] = *(const bf16x8*)(ldsB + rowb * 128 + ((c ^ (rowb & 7)) << 4));
      }
#pragma unroll
      for (int mt = 0; mt < 2; ++mt)
#pragma unroll
        for (int nt = 0; nt < 2; ++nt)
          acc[mt][nt] = __builtin_amdgcn_mfma_f32_32x32x16_bf16(
              af[mt], bfr[nt], acc[mt][nt], 0, 0, 0);
    }
    __syncthreads();
  }

  // epilogue: C layout 32x32: col=lane&31, row=(r&3)+8*(r>>2)+4*(lane>>5)
#pragma unroll
  for (int nt = 0; nt < 2; ++nt) {
    int g = bn0 + cn + nt * 32 + l31;
    float bv = bias[g];
#pragma unroll
    for (int mt = 0; mt < 2; ++mt) {
#pragma unroll
      for (int r = 0; r < 16; ++r) {
        int row = (r & 3) + 8 * (r >> 2) + 4 * l5;
        int bt = bm * 128 + rm + mt * 32 + row;
        int tt = bt & 511, bb = bt >> 9;
        xw[(size_t)(tt * 64 + bb) * NG + g] = (__bf16)(acc[mt][nt][r] + bv);
      }
    }
  }
}

// ---------------- persistent LSTM scan ----------------
// 256 blocks x 256 thr. block: ms=bid&3 -> batches [ms*16,+16); nj=bid>>2 -> j in [nj*16,+16)
// wave w K-splits [w*256,+256). U slice (64 gate-cols x 1024) lives in VGPRs.
__global__ __launch_bounds__(256, 1) void k_lstm(
    const int* __restrict__ ids, const __bf16* __restrict__ xw,
    const __bf16* __restrict__ Ut, float* __restrict__ out,
    __bf16* __restrict__ hbuf, unsigned* __restrict__ bar) {
  const int tid = threadIdx.x;
  const int lane = tid & 63, w = tid >> 6;
  const int bid = blockIdx.x;
  const int ms = bid & 3, nj = bid >> 2;
  const int b0 = ms * 16, j0 = nj * 16;

  const int bn = lane & 15;  // n (j-local) for B frags / MFMA
  const int kc = lane >> 4;  // k-chunk 0..3

  // load U fragments into registers (held across the whole scan)
  bf16x8 Bfrag[4][8];
#pragma unroll
  for (int q = 0; q < 4; ++q) {
#pragma unroll
    for (int ks = 0; ks < 8; ++ks) {
      int g = q * NH + j0 + bn;
      int k = w * 256 + ks * 32 + kc * 8;
      Bfrag[q][ks] = *(const bf16x8*)(Ut + (size_t)g * NH + k);
    }
  }

  // gate-phase element: thread -> (local batch eb, local j ej)
  const int eb = tid >> 4, ej = tid & 15;
  const int bg = b0 + eb, jg = j0 + ej;
  float c_st = 0.0f, h_st = 0.0f;

  __shared__ float zp[4][4][16][16];  // [wave][gate][b][j]

  unsigned* flag = bar;        // byte 0
  unsigned* root = bar + 32;   // byte 128
  unsigned* grp = bar + 64;    // byte 256, stride 128B
  const int grpid = (bid & 7) * 32;

  const int am = lane & 15;  // batch row for A frags

#pragma unroll 1
  for (int t = 0; t < NT; ++t) {
    // prefetch xw_t and mask (independent of h)
    const __bf16* xwp = xw + ((size_t)(t * 64 + bg) << 12) + jg;
    __bf16 xr0 = xwp[0], xr1 = xwp[NH], xr2 = xwp[2 * NH], xr3 = xwp[3 * NH];
    int idv = ids[bg * NT + t];

    // wait until h_t is globally visible
    if (tid == 0) {
      while (__hip_atomic_load(flag, __ATOMIC_RELAXED, __HIP_MEMORY_SCOPE_AGENT) <
             (unsigned)t) {}
    }
    __syncthreads();
    __builtin_amdgcn_fence(__ATOMIC_ACQUIRE, "agent");

    const __bf16* hb = hbuf + (size_t)(t & 1) * (NB * NH);
    bf16x8 A[8];
#pragma unroll
    for (int ks = 0; ks < 8; ++ks)
      A[ks] = *(const bf16x8*)(hb + (b0 + am) * NH + w * 256 + ks * 32 + kc * 8);

    f32x4 acc[4] = {{0, 0, 0, 0}, {0, 0, 0, 0}, {0, 0, 0, 0}, {0, 0, 0, 0}};
#pragma unroll
    for (int ks = 0; ks < 8; ++ks)
#pragma unroll
      for (int q = 0; q < 4; ++q)
        acc[q] = __builtin_amdgcn_mfma_f32_16x16x32_bf16(A[ks], Bfrag[q][ks],
                                                         acc[q], 0, 0, 0);

    // partials to LDS: C layout col=lane&15 (=j), row=kc*4+r (=b)
#pragma unroll
    for (int q = 0; q < 4; ++q)
#pragma unroll
      for (int r = 0; r < 4; ++r) zp[w][q][kc * 4 + r][bn] = acc[q][r];
    __syncthreads();

    // gate phase: 1 element per thread
    float z0 = zp[0][0][eb][ej] + zp[1][0][eb][ej] + zp[2][0][eb][ej] + zp[3][0][eb][ej] + (float)xr0;
    float z1 = zp[0][1][eb][ej] + zp[1][1][eb][ej] + zp[2][1][eb][ej] + zp[3][1][eb][ej] + (float)xr1;
    float z2 = zp[0][2][eb][ej] + zp[1][2][eb][ej] + zp[2][2][eb][ej] + zp[3][2][eb][ej] + (float)xr2;
    float z3 = zp[0][3][eb][ej] + zp[1][3][eb][ej] + zp[2][3][eb][ej] + zp[3][3][eb][ej] + (float)xr3;
    float iv = sigf(z0), fv = sigf(z1), gv = sigf(z2), ov = sigf(z3);
    float cn = fv * c_st + iv * gv;
    float hn = ov * sigf(cn);
    bool m = (idv != 0);
    c_st = m ? cn : c_st;
    h_st = m ? hn : h_st;

    // write h_{t+1} (bf16, for next step's A) and outs (f32)
    __bf16* hw = hbuf + (size_t)((t + 1) & 1) * (NB * NH);
    hw[bg * NH + jg] = (__bf16)h_st;
    out[(size_t)bg * (NT * NH) + (size_t)t * NH + jg] = h_st;

    // barrier arrive (release h writes to LLC first)
    __syncthreads();
    if (tid == 0) {
      __threadfence();
      unsigned old = __hip_atomic_fetch_add(grp + grpid, 1u, __ATOMIC_ACQ_REL,
                                            __HIP_MEMORY_SCOPE_AGENT);
      if (old == (unsigned)t * 32u + 31u) {
        unsigned o2 = __hip_atomic_fetch_add(root, 1u, __ATOMIC_ACQ_REL,
                                             __HIP_MEMORY_SCOPE_AGENT);
        if (o2 == (unsigned)t * 8u + 7u) {
          __hip_atomic_store(flag, (unsigned)(t + 1), __ATOMIC_RELEASE,
                             __HIP_MEMORY_SCOPE_AGENT);
        }
      }
    }
  }

  // final h, c
  out[33554432u + bg * NH + jg] = h_st;
  out[33554432u + 65536u + bg * NH + jg] = c_st;
}

// ---------------- launch ----------------
extern "C" void kernel_launch(void* const* d_in, const int* in_sizes, int n_in,
                              void* d_out, int out_size, void* d_ws, size_t ws_size,
                              hipStream_t stream) {
  const int* ids = (const int*)d_in[0];
  const float* E = (const float*)d_in[1];
  const float* W = (const float*)d_in[2];
  const float* U = (const float*)d_in[3];
  const float* bias = (const float*)d_in[4];
  char* ws = (char*)d_ws;
  __bf16* Ebf = (__bf16*)(ws + OFF_EB);
  __bf16* Wt = (__bf16*)(ws + OFF_WT);
  __bf16* Ut = (__bf16*)(ws + OFF_UT);
  __bf16* xw = (__bf16*)(ws + OFF_XW);
  __bf16* hbuf = (__bf16*)(ws + OFF_H);
  unsigned* bar = (unsigned*)(ws + OFF_BAR);
  float* out = (float*)d_out;

  // zero barrier + h buffers (266240 bytes)
  hipLaunchKernelGGL(k_zero, dim3(65), dim3(256), 0, stream, (uint4*)ws, 16640);
  // E -> bf16
  hipLaunchKernelGGL(k_cvt, dim3(2048), dim3(256), 0, stream, E, Ebf, 4096000);
  // W^T, U^T -> bf16
  hipLaunchKernelGGL(k_transpose, dim3(64, 8), dim3(256), 0, stream, W, Wt, 512, 4096);
  hipLaunchKernelGGL(k_transpose, dim3(64, 16), dim3(256), 0, stream, U, Ut, 1024, 4096);
  // xw = gather(E)@W + b
  hipLaunchKernelGGL(k_gemm_xw, dim3(8192), dim3(256), 0, stream, ids, Ebf, Wt, bias, xw);
  // persistent LSTM scan
  hipLaunchKernelGGL(k_lstm, dim3(256), dim3(256), 0, stream, ids, xw, Ut, out, hbuf, bar);
}

// Round 3
// 3468.510 us; speedup vs baseline: 3.2761x; 3.2761x over previous
//
#include <hip/hip_runtime.h>
#include <hip/hip_bf16.h>

typedef __bf16 bf16x8 __attribute__((ext_vector_type(8)));
typedef __bf16 bf16x4 __attribute__((ext_vector_type(4)));
typedef float  f32x4  __attribute__((ext_vector_type(4)));
typedef float  f32x16 __attribute__((ext_vector_type(16)));
typedef int    i32x4  __attribute__((ext_vector_type(4)));

// Problem dims
#define NB 64
#define NT 512
#define ND 512
#define NH 1024
#define NG 4096  // 4H

// workspace layout (bytes) — total 314,052,608
#define OFF_BAR 0u          // cnt @ byte 2048 (single relaxed arrival counter)
#define OFF_H   4096u       // h double buffer: 2 x 64 x 1024 bf16 = 256 KB
#define OFF_EB  266240u     // E as bf16: 32000x512
#define OFF_WT  33034240u   // W^T bf16: 4096x512
#define OFF_UT  37228544u   // U^T bf16: 4096x1024
#define OFF_XW  45617152u   // xw bf16: (T,B,4096) = 256 MB

__device__ __forceinline__ void gl_lds16(const void* g, void* l) {
  typedef const unsigned __attribute__((address_space(1)))* gp_t;
  typedef unsigned __attribute__((address_space(3)))* lp_t;
  __builtin_amdgcn_global_load_lds((gp_t)g, (lp_t)l, 16, 0, 0);
}

__device__ __forceinline__ float sigf(float x) {
  return 1.0f / (1.0f + __expf(-x));
}

// 8 coherent (LLC) 16B loads from consecutive 64B offsets + drain.
// Outputs are EARLY-CLOBBER: they must not alias the address pair, because
// loads 2..8 still read %[a] after load 1 has written its dest.
__device__ __forceinline__ void load_h_frags(unsigned long long a, i32x4* A) {
  asm volatile(
      "global_load_dwordx4 %0, %[a], off sc0 sc1\n\t"
      "global_load_dwordx4 %1, %[a], off offset:64 sc0 sc1\n\t"
      "global_load_dwordx4 %2, %[a], off offset:128 sc0 sc1\n\t"
      "global_load_dwordx4 %3, %[a], off offset:192 sc0 sc1\n\t"
      "global_load_dwordx4 %4, %[a], off offset:256 sc0 sc1\n\t"
      "global_load_dwordx4 %5, %[a], off offset:320 sc0 sc1\n\t"
      "global_load_dwordx4 %6, %[a], off offset:384 sc0 sc1\n\t"
      "global_load_dwordx4 %7, %[a], off offset:448 sc0 sc1\n\t"
      "s_waitcnt vmcnt(0)"
      : "=&v"(A[0]), "=&v"(A[1]), "=&v"(A[2]), "=&v"(A[3]),
        "=&v"(A[4]), "=&v"(A[5]), "=&v"(A[6]), "=&v"(A[7])
      : [a] "v"(a)
      : "memory");
}

// ---------------- prep kernels ----------------
__global__ void k_zero(uint4* p, int n) {
  int i = blockIdx.x * blockDim.x + threadIdx.x;
  int stride = gridDim.x * blockDim.x;
  uint4 z; z.x = 0; z.y = 0; z.z = 0; z.w = 0;
  for (; i < n; i += stride) p[i] = z;
}

__global__ void k_cvt(const float* __restrict__ in, __bf16* __restrict__ out, int n4) {
  int i = blockIdx.x * blockDim.x + threadIdx.x;
  int stride = gridDim.x * blockDim.x;
  for (; i < n4; i += stride) {
    float4 f = ((const float4*)in)[i];
    bf16x4 o;
    o.x = (__bf16)f.x; o.y = (__bf16)f.y; o.z = (__bf16)f.z; o.w = (__bf16)f.w;
    ((bf16x4*)out)[i] = o;
  }
}

// out[c][r] = (bf16) in[r][c];  in is (R,C) f32, out is (C,R) bf16
__global__ void k_transpose(const float* __restrict__ in, __bf16* __restrict__ out,
                            int R, int C) {
  __shared__ __bf16 tile[64][72];
  int c0 = blockIdx.x * 64, r0 = blockIdx.y * 64;
  for (int i = threadIdx.x; i < 4096; i += 256) {
    int r = i >> 6, c = i & 63;
    tile[r][c] = (__bf16)in[(size_t)(r0 + r) * C + c0 + c];
  }
  __syncthreads();
  for (int i = threadIdx.x; i < 4096; i += 256) {
    int c = i >> 6, r = i & 63;
    out[(size_t)(c0 + c) * R + r0 + r] = tile[r][c];
  }
}

// ---------------- GEMM1: xw[t][b][g] = E[ids[bt]] @ W + b ----------------
__global__ __launch_bounds__(256, 2) void k_gemm_xw(
    const int* __restrict__ ids, const __bf16* __restrict__ Ebf,
    const __bf16* __restrict__ Wt, const float* __restrict__ bias,
    __bf16* __restrict__ xw) {
  __shared__ __align__(16) char smem[32768];  // A tile 16K + B tile 16K
  char* ldsA = smem;
  char* ldsB = smem + 16384;

  const int tid = threadIdx.x;
  const int lane = tid & 63, w = tid >> 6;
  const int bm = blockIdx.x >> 5;          // 0..255
  const int bn0 = (blockIdx.x & 31) * 128; // col base

  const int l8r = lane >> 3, pc = lane & 7;
  size_t asrc[4], bsrc[4];
#pragma unroll
  for (int is = 0; is < 4; ++is) {
    int row = w * 32 + is * 8 + l8r;
    int id = ids[bm * 128 + row];
    asrc[is] = (size_t)id * ND + (size_t)(((pc ^ (row & 7)) * 8));
    int gn = bn0 + row;
    bsrc[is] = (size_t)gn * ND + (size_t)(((pc ^ (row & 7)) * 8));
  }

  const int rm = (w & 1) * 64, cn = (w >> 1) * 64;
  const int l31 = lane & 31, l5 = lane >> 5;
  f32x16 acc[2][2] = {};

  for (int kk = 0; kk < 8; ++kk) {
#pragma unroll
    for (int is = 0; is < 4; ++is) {
      gl_lds16(Ebf + asrc[is] + kk * 64, ldsA + w * 4096 + is * 1024);
      gl_lds16(Wt + bsrc[is] + kk * 64, ldsB + w * 4096 + is * 1024);
    }
    __syncthreads();
#pragma unroll
    for (int ksub = 0; ksub < 4; ++ksub) {
      int c = ksub * 2 + l5;
      bf16x8 af[2], bfr[2];
#pragma unroll
      for (int mt = 0; mt < 2; ++mt) {
        int row = rm + mt * 32 + l31;
        af[mt] = *(const bf16x8*)(ldsA + row * 128 + ((c ^ (row & 7)) << 4));
      }
#pragma unroll
      for (int nt = 0; nt < 2; ++nt) {
        int rowb = cn + nt * 32 + l31;
        bfr[nt] = *(const bf16x8*)(ldsB + rowb * 128 + ((c ^ (rowb & 7)) << 4));
      }
#pragma unroll
      for (int mt = 0; mt < 2; ++mt)
#pragma unroll
        for (int nt = 0; nt < 2; ++nt)
          acc[mt][nt] = __builtin_amdgcn_mfma_f32_32x32x16_bf16(
              af[mt], bfr[nt], acc[mt][nt], 0, 0, 0);
    }
    __syncthreads();
  }

#pragma unroll
  for (int nt = 0; nt < 2; ++nt) {
    int g = bn0 + cn + nt * 32 + l31;
    float bv = bias[g];
#pragma unroll
    for (int mt = 0; mt < 2; ++mt) {
#pragma unroll
      for (int r = 0; r < 16; ++r) {
        int row = (r & 3) + 8 * (r >> 2) + 4 * l5;
        int bt = bm * 128 + rm + mt * 32 + row;
        int tt = bt & 511, bb = bt >> 9;
        xw[(size_t)(tt * 64 + bb) * NG + g] = (__bf16)(acc[mt][nt][r] + bv);
      }
    }
  }
}

// ---------------- persistent LSTM scan ----------------
// 256 blocks x 256 thr. block: ms=bid&3 -> batches [ms*16,+16); nj=bid>>2 -> j in [nj*16,+16)
// wave w K-splits [w*256,+256).
// All cross-block traffic is sc0sc1 (LLC-coherent); NO fences in the loop.
__global__ __launch_bounds__(256, 1) void k_lstm(
    const int* __restrict__ ids, const __bf16* __restrict__ xw,
    const __bf16* __restrict__ Ut, float* __restrict__ out,
    __bf16* __restrict__ hbuf, unsigned* __restrict__ bar) {
  const int tid = threadIdx.x;
  const int lane = tid & 63, w = tid >> 6;
  const int bid = blockIdx.x;
  const int ms = bid & 3, nj = bid >> 2;
  const int b0 = ms * 16, j0 = nj * 16;

  const int bn = lane & 15;  // n (j-local) for B frags / MFMA
  const int kc = lane >> 4;  // k-chunk 0..3

  // U fragments (compiler may keep in regs or re-load from L2 — both fine)
  bf16x8 Bfrag[4][8];
#pragma unroll
  for (int q = 0; q < 4; ++q) {
#pragma unroll
    for (int ks = 0; ks < 8; ++ks) {
      int g = q * NH + j0 + bn;
      int k = w * 256 + ks * 32 + kc * 8;
      Bfrag[q][ks] = *(const bf16x8*)(Ut + (size_t)g * NH + k);
    }
  }

  const int eb = tid >> 4, ej = tid & 15;
  const int bg = b0 + eb, jg = j0 + ej;
  float c_st = 0.0f, h_st = 0.0f;

  __shared__ float zp[4][4][16][16];  // [wave][gate][b][j]

  unsigned* cnt = bar + 512;  // byte 2048, zeroed each launch
  const int am = lane & 15;   // batch row for A frags

  const unsigned long long hbase =
      (unsigned long long)(hbuf) + ((b0 + am) * NH + w * 256 + kc * 8) * 2ull;
  const unsigned long long hwaddr0 =
      (unsigned long long)(hbuf) + (bg * NH + jg) * 2ull;

#pragma unroll 1
  for (int t = 0; t < NT; ++t) {
    // prefetch xw_t and mask (independent of h) — overlaps the spin
    const __bf16* xwp = xw + ((size_t)(t * 64 + bg) << 12) + jg;
    __bf16 xr0 = xwp[0], xr1 = xwp[NH], xr2 = xwp[2 * NH], xr3 = xwp[3 * NH];
    int idv = ids[bg * NT + t];

    // wait until all blocks finished step t-1 (cnt >= t*256); coherent poll.
    // dest is early-clobber so it can never alias the address pair.
    if (tid == 0) {
      unsigned v;
      do {
        asm volatile(
            "global_load_dword %0, %[a], off sc0 sc1\n\t"
            "s_waitcnt vmcnt(0)"
            : "=&v"(v) : [a] "v"((unsigned long long)cnt) : "memory");
      } while (v < (unsigned)(t << 8));
    }
    __syncthreads();

    // h_t fragments straight from LLC
    i32x4 Ar[8];
    load_h_frags(hbase + (unsigned long long)((t & 1) * (NB * NH * 2)), Ar);

    f32x4 acc[4] = {{0, 0, 0, 0}, {0, 0, 0, 0}, {0, 0, 0, 0}, {0, 0, 0, 0}};
#pragma unroll
    for (int ks = 0; ks < 8; ++ks) {
      bf16x8 a = __builtin_bit_cast(bf16x8, Ar[ks]);
#pragma unroll
      for (int q = 0; q < 4; ++q)
        acc[q] = __builtin_amdgcn_mfma_f32_16x16x32_bf16(a, Bfrag[q][ks],
                                                         acc[q], 0, 0, 0);
    }

    // partials to LDS: C layout col=lane&15 (=j), row=kc*4+r (=b)
#pragma unroll
    for (int q = 0; q < 4; ++q)
#pragma unroll
      for (int r = 0; r < 4; ++r) zp[w][q][kc * 4 + r][bn] = acc[q][r];
    __syncthreads();

    float z0 = zp[0][0][eb][ej] + zp[1][0][eb][ej] + zp[2][0][eb][ej] + zp[3][0][eb][ej] + (float)xr0;
    float z1 = zp[0][1][eb][ej] + zp[1][1][eb][ej] + zp[2][1][eb][ej] + zp[3][1][eb][ej] + (float)xr1;
    float z2 = zp[0][2][eb][ej] + zp[1][2][eb][ej] + zp[2][2][eb][ej] + zp[3][2][eb][ej] + (float)xr2;
    float z3 = zp[0][3][eb][ej] + zp[1][3][eb][ej] + zp[2][3][eb][ej] + zp[3][3][eb][ej] + (float)xr3;
    float iv = sigf(z0), fv = sigf(z1), gv = sigf(z2), ov = sigf(z3);
    float cn = fv * c_st + iv * gv;
    float hn = ov * sigf(cn);
    bool m = (idv != 0);
    c_st = m ? cn : c_st;
    h_st = m ? hn : h_st;

    // outs (f32, normal cached store — never read back by us)
    out[(size_t)bg * (NT * NH) + (size_t)t * NH + jg] = h_st;

    // h_{t+1} write-through to LLC, then drain THIS wave's stores
    {
      unsigned hv = (unsigned)__builtin_bit_cast(unsigned short, (__bf16)h_st);
      unsigned long long ha =
          hwaddr0 + (unsigned long long)(((t + 1) & 1) * (NB * NH * 2));
      asm volatile(
          "global_store_short %[a], %[d], off sc0 sc1\n\t"
          "s_waitcnt vmcnt(0)"
          :: [a] "v"(ha), [d] "v"(hv) : "memory");
    }
    __syncthreads();  // all waves drained -> tid0 may arrive

    if (tid == 0) {
      __hip_atomic_fetch_add(cnt, 1u, __ATOMIC_RELAXED,
                             __HIP_MEMORY_SCOPE_AGENT);
    }
  }

  // final h, c
  out[33554432u + bg * NH + jg] = h_st;
  out[33554432u + 65536u + bg * NH + jg] = c_st;
}

// ---------------- launch ----------------
extern "C" void kernel_launch(void* const* d_in, const int* in_sizes, int n_in,
                              void* d_out, int out_size, void* d_ws, size_t ws_size,
                              hipStream_t stream) {
  const int* ids = (const int*)d_in[0];
  const float* E = (const float*)d_in[1];
  const float* W = (const float*)d_in[2];
  const float* U = (const float*)d_in[3];
  const float* bias = (const float*)d_in[4];
  char* ws = (char*)d_ws;
  __bf16* Ebf = (__bf16*)(ws + OFF_EB);
  __bf16* Wt = (__bf16*)(ws + OFF_WT);
  __bf16* Ut = (__bf16*)(ws + OFF_UT);
  __bf16* xw = (__bf16*)(ws + OFF_XW);
  __bf16* hbuf = (__bf16*)(ws + OFF_H);
  unsigned* bar = (unsigned*)(ws + OFF_BAR);
  float* out = (float*)d_out;

  // zero barrier + h buffers (266240 bytes)
  hipLaunchKernelGGL(k_zero, dim3(65), dim3(256), 0, stream, (uint4*)ws, 16640);
  // E -> bf16
  hipLaunchKernelGGL(k_cvt, dim3(2048), dim3(256), 0, stream, E, Ebf, 4096000);
  // W^T, U^T -> bf16
  hipLaunchKernelGGL(k_transpose, dim3(64, 8), dim3(256), 0, stream, W, Wt, 512, 4096);
  hipLaunchKernelGGL(k_transpose, dim3(64, 16), dim3(256), 0, stream, U, Ut, 1024, 4096);
  // xw = gather(E)@W + b
  hipLaunchKernelGGL(k_gemm_xw, dim3(8192), dim3(256), 0, stream, ids, Ebf, Wt, bias, xw);
  // persistent LSTM scan
  hipLaunchKernelGGL(k_lstm, dim3(256), dim3(256), 0, stream, ids, xw, Ut, out, hbuf, bar);
}

// Round 4
// 2523.600 us; speedup vs baseline: 4.5028x; 1.3744x over previous
//
#include <hip/hip_runtime.h>
#include <hip/hip_bf16.h>

typedef __bf16 bf16x8 __attribute__((ext_vector_type(8)));
typedef __bf16 bf16x4 __attribute__((ext_vector_type(4)));
typedef float  f32x4  __attribute__((ext_vector_type(4)));
typedef float  f32x16 __attribute__((ext_vector_type(16)));
typedef int    i32x4  __attribute__((ext_vector_type(4)));

// Problem dims
#define NB 64
#define NT 512
#define ND 512
#define NH 1024
#define NG 4096  // 4H

// workspace layout (bytes) — total 314,052,608
#define OFF_BAR 0u          // 32 arrival counters, 128B stride (4 KB)
#define OFF_H   4096u       // h double buffer: 2 x 64 x 1024 bf16 = 256 KB
#define OFF_EB  266240u     // E as bf16: 32000x512
#define OFF_WT  33034240u   // W^T bf16: 4096x512
#define OFF_UT  37228544u   // U^T bf16: 4096x1024
#define OFF_XW  45617152u   // xw bf16: (T,B,4096) = 256 MB

__device__ __forceinline__ void gl_lds16(const void* g, void* l) {
  typedef const unsigned __attribute__((address_space(1)))* gp_t;
  typedef unsigned __attribute__((address_space(3)))* lp_t;
  __builtin_amdgcn_global_load_lds((gp_t)g, (lp_t)l, 16, 0, 0);
}

__device__ __forceinline__ float sigf(float x) {
  return 1.0f / (1.0f + __expf(-x));
}

// 8 coherent (LLC) 16B loads from consecutive 64B offsets + drain.
// Outputs EARLY-CLOBBER: must not alias the address pair.
__device__ __forceinline__ void load_h_frags(unsigned long long a, i32x4* A) {
  asm volatile(
      "global_load_dwordx4 %0, %[a], off sc0 sc1\n\t"
      "global_load_dwordx4 %1, %[a], off offset:64 sc0 sc1\n\t"
      "global_load_dwordx4 %2, %[a], off offset:128 sc0 sc1\n\t"
      "global_load_dwordx4 %3, %[a], off offset:192 sc0 sc1\n\t"
      "global_load_dwordx4 %4, %[a], off offset:256 sc0 sc1\n\t"
      "global_load_dwordx4 %5, %[a], off offset:320 sc0 sc1\n\t"
      "global_load_dwordx4 %6, %[a], off offset:384 sc0 sc1\n\t"
      "global_load_dwordx4 %7, %[a], off offset:448 sc0 sc1\n\t"
      "s_waitcnt vmcnt(0)"
      : "=&v"(A[0]), "=&v"(A[1]), "=&v"(A[2]), "=&v"(A[3]),
        "=&v"(A[4]), "=&v"(A[5]), "=&v"(A[6]), "=&v"(A[7])
      : [a] "v"(a)
      : "memory");
}

// ---------------- prep kernels ----------------
__global__ void k_zero(uint4* p, int n) {
  int i = blockIdx.x * blockDim.x + threadIdx.x;
  int stride = gridDim.x * blockDim.x;
  uint4 z; z.x = 0; z.y = 0; z.z = 0; z.w = 0;
  for (; i < n; i += stride) p[i] = z;
}

__global__ void k_cvt(const float* __restrict__ in, __bf16* __restrict__ out, int n4) {
  int i = blockIdx.x * blockDim.x + threadIdx.x;
  int stride = gridDim.x * blockDim.x;
  for (; i < n4; i += stride) {
    float4 f = ((const float4*)in)[i];
    bf16x4 o;
    o.x = (__bf16)f.x; o.y = (__bf16)f.y; o.z = (__bf16)f.z; o.w = (__bf16)f.w;
    ((bf16x4*)out)[i] = o;
  }
}

// out[c][r] = (bf16) in[r][c];  in is (R,C) f32, out is (C,R) bf16
__global__ void k_transpose(const float* __restrict__ in, __bf16* __restrict__ out,
                            int R, int C) {
  __shared__ __bf16 tile[64][72];
  int c0 = blockIdx.x * 64, r0 = blockIdx.y * 64;
  for (int i = threadIdx.x; i < 4096; i += 256) {
    int r = i >> 6, c = i & 63;
    tile[r][c] = (__bf16)in[(size_t)(r0 + r) * C + c0 + c];
  }
  __syncthreads();
  for (int i = threadIdx.x; i < 4096; i += 256) {
    int c = i >> 6, r = i & 63;
    out[(size_t)(c0 + c) * R + r0 + r] = tile[r][c];
  }
}

// ---------------- GEMM1: xw[t][b][g] = E[ids[bt]] @ W + b ----------------
__global__ __launch_bounds__(256, 2) void k_gemm_xw(
    const int* __restrict__ ids, const __bf16* __restrict__ Ebf,
    const __bf16* __restrict__ Wt, const float* __restrict__ bias,
    __bf16* __restrict__ xw) {
  __shared__ __align__(16) char smem[32768];  // A tile 16K + B tile 16K
  char* ldsA = smem;
  char* ldsB = smem + 16384;

  const int tid = threadIdx.x;
  const int lane = tid & 63, w = tid >> 6;
  const int bm = blockIdx.x >> 5;          // 0..255
  const int bn0 = (blockIdx.x & 31) * 128; // col base

  const int l8r = lane >> 3, pc = lane & 7;
  size_t asrc[4], bsrc[4];
#pragma unroll
  for (int is = 0; is < 4; ++is) {
    int row = w * 32 + is * 8 + l8r;
    int id = ids[bm * 128 + row];
    asrc[is] = (size_t)id * ND + (size_t)(((pc ^ (row & 7)) * 8));
    int gn = bn0 + row;
    bsrc[is] = (size_t)gn * ND + (size_t)(((pc ^ (row & 7)) * 8));
  }

  const int rm = (w & 1) * 64, cn = (w >> 1) * 64;
  const int l31 = lane & 31, l5 = lane >> 5;
  f32x16 acc[2][2] = {};

  for (int kk = 0; kk < 8; ++kk) {
#pragma unroll
    for (int is = 0; is < 4; ++is) {
      gl_lds16(Ebf + asrc[is] + kk * 64, ldsA + w * 4096 + is * 1024);
      gl_lds16(Wt + bsrc[is] + kk * 64, ldsB + w * 4096 + is * 1024);
    }
    __syncthreads();
#pragma unroll
    for (int ksub = 0; ksub < 4; ++ksub) {
      int c = ksub * 2 + l5;
      bf16x8 af[2], bfr[2];
#pragma unroll
      for (int mt = 0; mt < 2; ++mt) {
        int row = rm + mt * 32 + l31;
        af[mt] = *(const bf16x8*)(ldsA + row * 128 + ((c ^ (row & 7)) << 4));
      }
#pragma unroll
      for (int nt = 0; nt < 2; ++nt) {
        int rowb = cn + nt * 32 + l31;
        bfr[nt] = *(const bf16x8*)(ldsB + rowb * 128 + ((c ^ (rowb & 7)) << 4));
      }
#pragma unroll
      for (int mt = 0; mt < 2; ++mt)
#pragma unroll
        for (int nt = 0; nt < 2; ++nt)
          acc[mt][nt] = __builtin_amdgcn_mfma_f32_32x32x16_bf16(
              af[mt], bfr[nt], acc[mt][nt], 0, 0, 0);
    }
    __syncthreads();
  }

#pragma unroll
  for (int nt = 0; nt < 2; ++nt) {
    int g = bn0 + cn + nt * 32 + l31;
    float bv = bias[g];
#pragma unroll
    for (int mt = 0; mt < 2; ++mt) {
#pragma unroll
      for (int r = 0; r < 16; ++r) {
        int row = (r & 3) + 8 * (r >> 2) + 4 * l5;
        int bt = bm * 128 + rm + mt * 32 + row;
        int tt = bt & 511, bb = bt >> 9;
        xw[(size_t)(tt * 64 + bb) * NG + g] = (__bf16)(acc[mt][nt][r] + bv);
      }
    }
  }
}

// ---------------- persistent LSTM scan ----------------
// 256 blocks x 256 thr. block: ms=bid&3 -> batches [ms*16,+16); nj=bid>>2 -> j in [nj*16,+16)
// wave w K-splits [w*256,+256). U slice (64 gate-cols x 1024 K, 128 KB) lives
// in LDS in fragment order (conflict-free ds_read_b128).
// Barrier: 32 scatter counters (128B apart); arrivals 8-way serialized per line,
// wave 0 polls all lines with one 64-lane coherent load + __all.
__global__ __launch_bounds__(256, 1) void k_lstm(
    const int* __restrict__ ids, const __bf16* __restrict__ xw,
    const __bf16* __restrict__ Ut, float* __restrict__ out,
    __bf16* __restrict__ hbuf, unsigned* __restrict__ bar) {
  extern __shared__ char dynlds[];
  char* ubuf = dynlds;                       // 131072 B: U fragments
  float* zp = (float*)(dynlds + 131072);     // 16384 B: [wv][q][16b][16j]

  const int tid = threadIdx.x;
  const int lane = tid & 63, w = tid >> 6;
  const int bid = blockIdx.x;
  const int ms = bid & 3, nj = bid >> 2;
  const int b0 = ms * 16, j0 = nj * 16;

  const int bn = lane & 15;  // n (j-local) for B frags / MFMA
  const int kc = lane >> 4;  // k-chunk 0..3

  // stage U fragments into LDS once, in exact fragment order:
  // frag (w,q,ks) for lane L sits at ((w*4+q)*8+ks)*1024 + L*16.
#pragma unroll
  for (int q = 0; q < 4; ++q) {
#pragma unroll
    for (int ks = 0; ks < 8; ++ks) {
      const __bf16* src =
          Ut + (size_t)(q * NH + j0 + bn) * NH + w * 256 + ks * 32 + kc * 8;
      gl_lds16(src, ubuf + (((w * 4 + q) * 8 + ks) << 10));
    }
  }
  __syncthreads();

  const int eb = tid >> 4, ej = tid & 15;
  const int bg = b0 + eb, jg = j0 + ej;
  float c_st = 0.0f, h_st = 0.0f;

  const int am = lane & 15;  // batch row for A frags
  const unsigned long long hbase =
      (unsigned long long)(hbuf) + ((b0 + am) * NH + w * 256 + kc * 8) * 2ull;
  const unsigned long long hwaddr0 =
      (unsigned long long)(hbuf) + (bg * NH + jg) * 2ull;
  const unsigned long long pollA =
      (unsigned long long)(bar) + (unsigned long long)((lane & 31) << 7);

#pragma unroll 1
  for (int t = 0; t < NT; ++t) {
    // prefetch xw_t and mask (independent of h) — overlaps the spin
    const __bf16* xwp = xw + ((size_t)(t * 64 + bg) << 12) + jg;
    __bf16 xr0 = xwp[0], xr1 = xwp[NH], xr2 = xwp[2 * NH], xr3 = xwp[3 * NH];
    int idv = ids[bg * NT + t];

    // wait until all 256 blocks finished step t-1: every line >= t*8
    if (w == 0) {
      const unsigned tgt = (unsigned)(t << 3);
      bool ok;
      do {
        unsigned v;
        asm volatile(
            "global_load_dword %0, %[a], off sc0 sc1\n\t"
            "s_waitcnt vmcnt(0)"
            : "=&v"(v) : [a] "v"(pollA) : "memory");
        ok = __all((int)(v >= tgt));
      } while (!ok);
    }
    __syncthreads();

    // h_t fragments straight from LLC
    i32x4 Ar[8];
    load_h_frags(hbase + (unsigned long long)((t & 1) * (NB * NH * 2)), Ar);

    f32x4 acc[4] = {{0, 0, 0, 0}, {0, 0, 0, 0}, {0, 0, 0, 0}, {0, 0, 0, 0}};
#pragma unroll
    for (int ks = 0; ks < 8; ++ks) {
      bf16x8 a = __builtin_bit_cast(bf16x8, Ar[ks]);
#pragma unroll
      for (int q = 0; q < 4; ++q) {
        bf16x8 bfr =
            *(const bf16x8*)(ubuf + ((((w * 4 + q) * 8 + ks) << 6) + lane) * 16);
        acc[q] = __builtin_amdgcn_mfma_f32_16x16x32_bf16(a, bfr, acc[q], 0, 0, 0);
      }
    }

    // partials to LDS: C layout col=lane&15 (=j), row=kc*4+r (=b)
#pragma unroll
    for (int q = 0; q < 4; ++q)
#pragma unroll
      for (int r = 0; r < 4; ++r)
        zp[((w * 4 + q) << 8) + ((kc * 4 + r) << 4) + bn] = acc[q][r];
    __syncthreads();

    float z0 = 0, z1 = 0, z2 = 0, z3 = 0;
#pragma unroll
    for (int wv = 0; wv < 4; ++wv) {
      z0 += zp[((wv * 4 + 0) << 8) + (eb << 4) + ej];
      z1 += zp[((wv * 4 + 1) << 8) + (eb << 4) + ej];
      z2 += zp[((wv * 4 + 2) << 8) + (eb << 4) + ej];
      z3 += zp[((wv * 4 + 3) << 8) + (eb << 4) + ej];
    }
    z0 += (float)xr0; z1 += (float)xr1; z2 += (float)xr2; z3 += (float)xr3;
    float iv = sigf(z0), fv = sigf(z1), gv = sigf(z2), ov = sigf(z3);
    float cn = fv * c_st + iv * gv;
    float hn = ov * sigf(cn);
    bool m = (idv != 0);
    c_st = m ? cn : c_st;
    h_st = m ? hn : h_st;

    // outs (f32, normal cached store — never read back by us)
    out[(size_t)bg * (NT * NH) + (size_t)t * NH + jg] = h_st;

    // h_{t+1} write-through to LLC, then drain THIS wave's stores
    {
      unsigned hv = (unsigned)__builtin_bit_cast(unsigned short, (__bf16)h_st);
      unsigned long long ha =
          hwaddr0 + (unsigned long long)(((t + 1) & 1) * (NB * NH * 2));
      asm volatile(
          "global_store_short %[a], %[d], off sc0 sc1\n\t"
          "s_waitcnt vmcnt(0)"
          :: [a] "v"(ha), [d] "v"(hv) : "memory");
    }
    __syncthreads();  // all waves drained -> tid0 may arrive

    if (tid == 0) {
      __hip_atomic_fetch_add(bar + ((bid & 31) << 5), 1u, __ATOMIC_RELAXED,
                             __HIP_MEMORY_SCOPE_AGENT);
    }
  }

  // final h, c
  out[33554432u + bg * NH + jg] = h_st;
  out[33554432u + 65536u + bg * NH + jg] = c_st;
}

// ---------------- launch ----------------
extern "C" void kernel_launch(void* const* d_in, const int* in_sizes, int n_in,
                              void* d_out, int out_size, void* d_ws, size_t ws_size,
                              hipStream_t stream) {
  const int* ids = (const int*)d_in[0];
  const float* E = (const float*)d_in[1];
  const float* W = (const float*)d_in[2];
  const float* U = (const float*)d_in[3];
  const float* bias = (const float*)d_in[4];
  char* ws = (char*)d_ws;
  __bf16* Ebf = (__bf16*)(ws + OFF_EB);
  __bf16* Wt = (__bf16*)(ws + OFF_WT);
  __bf16* Ut = (__bf16*)(ws + OFF_UT);
  __bf16* xw = (__bf16*)(ws + OFF_XW);
  __bf16* hbuf = (__bf16*)(ws + OFF_H);
  unsigned* bar = (unsigned*)(ws + OFF_BAR);
  float* out = (float*)d_out;

  // allow 144 KB dynamic LDS for k_lstm (idempotent; safe under graph capture)
  (void)hipFuncSetAttribute((const void*)k_lstm,
                            hipFuncAttributeMaxDynamicSharedMemorySize, 147456);

  // zero barrier + h buffers (266240 bytes)
  hipLaunchKernelGGL(k_zero, dim3(65), dim3(256), 0, stream, (uint4*)ws, 16640);
  // E -> bf16
  hipLaunchKernelGGL(k_cvt, dim3(2048), dim3(256), 0, stream, E, Ebf, 4096000);
  // W^T, U^T -> bf16
  hipLaunchKernelGGL(k_transpose, dim3(64, 8), dim3(256), 0, stream, W, Wt, 512, 4096);
  hipLaunchKernelGGL(k_transpose, dim3(64, 16), dim3(256), 0, stream, U, Ut, 1024, 4096);
  // xw = gather(E)@W + b
  hipLaunchKernelGGL(k_gemm_xw, dim3(8192), dim3(256), 0, stream, ids, Ebf, Wt, bias, xw);
  // persistent LSTM scan
  hipLaunchKernelGGL(k_lstm, dim3(256), dim3(256), 147456, stream, ids, xw, Ut, out, hbuf, bar);
}